// Round 1
// baseline (458.893 us; speedup 1.0000x reference)
//
#include <hip/hip_runtime.h>
#include <cstdint>
#include <cstddef>

#define NN 500000            // nodes = 16 * 31250 exactly
#define NTILES 31250         // 16-node tiles
#define NG 7813              // 64-node granules (4 tiles; last has 2)
#define NBLK 2048            // 128-thread blocks; 8/CU (VGPR-capped) -> 16 waves/CU
#define NWAVES (NBLK * 2)
// IN_CH=64, HEADS=4, OUT_CH=32, F=128 out feats, GH=256 gate hidden, SEGS=1024

typedef __attribute__((ext_vector_type(8))) short short8;   // 8 bf16 MFMA frag
typedef __attribute__((ext_vector_type(4))) float floatx4;  // MFMA accumulator
typedef __attribute__((ext_vector_type(4))) float fv4;

__device__ __forceinline__ unsigned short f2bf(float f) {
  union { float f; unsigned u; } v; v.f = f;
  unsigned r = v.u + 0x7FFFu + ((v.u >> 16) & 1u);  // RNE
  return (unsigned short)(r >> 16);
}
__device__ __forceinline__ unsigned pack2bf(float a, float b) {
  return (unsigned)f2bf(a) | ((unsigned)f2bf(b) << 16);
}
__device__ __forceinline__ fv4 ntload4(const float* p) {
  return __builtin_nontemporal_load((const fv4*)p);
}

#define MFMA16(a, b, c) __builtin_amdgcn_mfma_f32_16x16x32_bf16((a), (b), (c), 0, 0, 0)

// ---------------------------------------------------------------------------
// Kernel W: fp32 weights -> bf16 MFMA A-fragment order (gw1 / mw1 / mw2 only;
// gw2 is consumed as fp32 via LDS in the fused kernel). Also zeroes the
// denom/out accumulators (folds the two hipMemsetAsync launches).
// dst[((mtile*ksteps+ks)*64+lane)*8+j] = W[mtile*16+(lane&15)][ks*32+(lane>>4)*8+j]
// ---------------------------------------------------------------------------
__global__ void swizzle_weights(const float* __restrict__ gw1, const float* __restrict__ mw1,
                                const float* __restrict__ mw2,
                                unsigned short* __restrict__ gw1s,
                                unsigned short* __restrict__ mw1s,
                                unsigned short* __restrict__ mw2s,
                                float* __restrict__ denom, float* __restrict__ out) {
  int e = blockIdx.x * 256 + threadIdx.x;   // 40960 total
  if (e < 4096) denom[e] = 0.f;
#pragma unroll
  for (int i = 0; i < 4; ++i) {             // 131072 = 1024 segs * 128 fcols
    int o = e + i * 40960;
    if (o < 131072) out[o] = 0.f;
  }
  const float* src; unsigned short* dst; int ksteps, K, local;
  if (e < 16384)      { src = gw1; dst = gw1s; ksteps = 2; K = 64;  local = e; }
  else if (e < 24576) { src = mw1; dst = mw1s; ksteps = 2; K = 64;  local = e - 16384; }
  else                { src = mw2; dst = mw2s; ksteps = 4; K = 128; local = e - 24576; }
  int j = local & 7, lane = (local >> 3) & 63, tile = local >> 9;
  int ks = tile % ksteps, mtile = tile / ksteps;
  int row = mtile * 16 + (lane & 15);
  int k   = ks * 32 + ((lane >> 4) & 3) * 8 + j;
  dst[local] = f2bf(src[row * K + k]);
}

#define FLUSH() do {                                                          \
  _Pragma("unroll") for (int mt_ = 0; mt_ < 8; ++mt_) {                       \
    _Pragma("unroll") for (int r_ = 0; r_ < 4; ++r_) {                        \
      float v_ = acc[mt_][r_];                                                \
      v_ += __shfl_xor(v_, 1); v_ += __shfl_xor(v_, 2);                       \
      v_ += __shfl_xor(v_, 4); v_ += __shfl_xor(v_, 8);                       \
      if (lcol == 0)                                                          \
        atomicAdd(&out[cur_seg * 128 + mt_ * 16 + quad * 4 + r_], v_);        \
      acc[mt_][r_] = 0.f; } }                                                 \
  _Pragma("unroll") for (int h_ = 0; h_ < 4; ++h_) {                          \
    float v_ = e_sum[h_];                                                     \
    v_ += __shfl_xor(v_, 1); v_ += __shfl_xor(v_, 2);                         \
    v_ += __shfl_xor(v_, 4); v_ += __shfl_xor(v_, 8);                         \
    if (lane == 0) atomicAdd(&denom[cur_seg * 4 + h_], v_);                   \
    e_sum[h_] = 0.f; }                                                        \
} while (0)

// ---------------------------------------------------------------------------
// Fused kernel, barrier-free after prologue: each WAVE owns contiguous 64-node
// granules. Weights streamed from global (L2-resident; x is nontemporal so it
// can't evict them), amortized over node-tiles per fragment load.
// Gate L2 (4-wide) fused into gate L1 epilogue in VALU via gw2^T in LDS.
// MLP-L1 staging is per-16-node-tile (4.2 KB/wave instead of 16.9 KB) so the
// block fits 12.5 KB LDS -> occupancy is VGPR-capped at 8 blocks/CU (2x prev).
// Segment accumulation in registers, uniform run-loop, flush on seg change.
// ---------------------------------------------------------------------------
__global__ __launch_bounds__(128, 4) void fused_kernel(
    const float* __restrict__ x, const int* __restrict__ batch,
    const unsigned short* __restrict__ gw1s, const unsigned short* __restrict__ mw1s,
    const unsigned short* __restrict__ mw2s, const float* __restrict__ gw2,
    const float* __restrict__ prelu_a, const float* __restrict__ b1,
    float* __restrict__ denom, float* __restrict__ out) {
  __shared__ float gw2L[1024];                   // gw2^T [wcol][head], 4 KB
  __shared__ unsigned short hs_all[2][16 * 132]; // per-wave h1 staging, 2x4.2 KB
  const int t = threadIdx.x;
  const int wave = t >> 6, lane = t & 63;
  const int quad = lane >> 4, lcol = lane & 15;
  unsigned short* hs = hs_all[wave];

  for (int i = t; i < 1024; i += 128) gw2L[i] = gw2[(i & 3) * 256 + (i >> 2)];
  __syncthreads();   // only barrier in the kernel

  const float slope = prelu_a[0];
  const int W = blockIdx.x * 2 + wave;
  const int g0 = (int)(((long long)W * NG) / NWAVES);
  const int g1 = (int)(((long long)(W + 1) * NG) / NWAVES);

  float acc[8][4];
  float e_sum[4] = {0.f, 0.f, 0.f, 0.f};
#pragma unroll
  for (int mt = 0; mt < 8; ++mt)
#pragma unroll
    for (int r = 0; r < 4; ++r) acc[mt][r] = 0.f;
  int fs = g0 * 64; if (fs > NN - 1) fs = NN - 1;
  int cur_seg = batch[fs];

  for (int g = g0; g < g1; ++g) {
    const int base = g * 64;
    int sv[4]; float emask[4];
    short8 bx[4][2];
#pragma unroll
    for (int nt = 0; nt < 4; ++nt) {
      int tb = base + nt * 16;
      bool ok = tb < NN;               // NN%16==0 -> tile fully valid or fully not
      int node = ok ? (tb + lcol) : (NN - 1);
      emask[nt] = ok ? 1.f : 0.f;
      sv[nt] = batch[node];
      const float* xp = x + (size_t)node * 64 + quad * 8;
      fv4 v0 = ntload4(xp), v1 = ntload4(xp + 4);
      fv4 v2 = ntload4(xp + 32), v3 = ntload4(xp + 36);
      union { short8 s; unsigned u[4]; } u0, u1;
      u0.u[0] = pack2bf(v0[0], v0[1]); u0.u[1] = pack2bf(v0[2], v0[3]);
      u0.u[2] = pack2bf(v1[0], v1[1]); u0.u[3] = pack2bf(v1[2], v1[3]);
      u1.u[0] = pack2bf(v2[0], v2[1]); u1.u[1] = pack2bf(v2[2], v2[3]);
      u1.u[2] = pack2bf(v3[0], v3[1]); u1.u[3] = pack2bf(v3[2], v3[3]);
      bx[nt][0] = u0.s; bx[nt][1] = u1.s;
    }

    // ---- gate L1 (MFMA) with fused L2 partials (VALU, gw2L broadcast) ----
    float gp[4][4];
#pragma unroll
    for (int nt = 0; nt < 4; ++nt)
#pragma unroll
      for (int h = 0; h < 4; ++h) gp[nt][h] = 0.f;
#pragma unroll 2
    for (int mt = 0; mt < 16; ++mt) {
      short8 a0 = *(const short8*)(gw1s + ((size_t)(mt * 2 + 0) * 64 + lane) * 8);
      short8 a1 = *(const short8*)(gw1s + ((size_t)(mt * 2 + 1) * 64 + lane) * 8);
      fv4 g2r0 = *(const fv4*)&gw2L[(mt * 16 + quad * 4 + 0) * 4];
      fv4 g2r1 = *(const fv4*)&gw2L[(mt * 16 + quad * 4 + 1) * 4];
      fv4 g2r2 = *(const fv4*)&gw2L[(mt * 16 + quad * 4 + 2) * 4];
      fv4 g2r3 = *(const fv4*)&gw2L[(mt * 16 + quad * 4 + 3) * 4];
#pragma unroll
      for (int nt = 0; nt < 4; ++nt) {
        floatx4 cc = {0.f, 0.f, 0.f, 0.f};
        cc = MFMA16(a0, bx[nt][0], cc);
        cc = MFMA16(a1, bx[nt][1], cc);
        float h0 = cc[0] >= 0.f ? cc[0] : slope * cc[0];
        float h1v = cc[1] >= 0.f ? cc[1] : slope * cc[1];
        float h2 = cc[2] >= 0.f ? cc[2] : slope * cc[2];
        float h3 = cc[3] >= 0.f ? cc[3] : slope * cc[3];
        gp[nt][0] += g2r0[0]*h0 + g2r1[0]*h1v + g2r2[0]*h2 + g2r3[0]*h3;
        gp[nt][1] += g2r0[1]*h0 + g2r1[1]*h1v + g2r2[1]*h2 + g2r3[1]*h3;
        gp[nt][2] += g2r0[2]*h0 + g2r1[2]*h1v + g2r2[2]*h2 + g2r3[2]*h3;
        gp[nt][3] += g2r0[3]*h0 + g2r1[3]*h1v + g2r2[3]*h2 + g2r3[3]*h3;
      }
    }
    float e16[4][4];
#pragma unroll
    for (int nt = 0; nt < 4; ++nt)
#pragma unroll
      for (int h = 0; h < 4; ++h) {
        float v = gp[nt][h];
        v += __shfl_xor(v, 16);      // sum partials across quads
        v += __shfl_xor(v, 32);
        e16[nt][h] = __expf(v) * emask[nt];   // |gate| small -> no max needed
      }

    // ---- MLP L1 (MFMA) -> per-tile bf16 staging -> B-fragments for L2 ----
    // nt-outer so the staging buffer covers only 16 nodes (LDS 4x smaller);
    // wave-internal LDS ordering handles the write->read->overwrite chain.
    union BH { short8 s; uint2 u[2]; } bh[4][4];
#pragma unroll
    for (int nt = 0; nt < 4; ++nt) {
#pragma unroll 2
      for (int mt = 0; mt < 8; ++mt) {
        short8 a0 = *(const short8*)(mw1s + ((size_t)(mt * 2 + 0) * 64 + lane) * 8);
        short8 a1 = *(const short8*)(mw1s + ((size_t)(mt * 2 + 1) * 64 + lane) * 8);
        fv4 bias = *(const fv4*)(b1 + mt * 16 + quad * 4);
        floatx4 cc = {0.f, 0.f, 0.f, 0.f};
        cc = MFMA16(a0, bx[nt][0], cc);
        cc = MFMA16(a1, bx[nt][1], cc);
        uint2 p;
        p.x = pack2bf(fmaxf(cc[0] + bias[0], 0.f), fmaxf(cc[1] + bias[1], 0.f));
        p.y = pack2bf(fmaxf(cc[2] + bias[2], 0.f), fmaxf(cc[3] + bias[3], 0.f));
        *(uint2*)(hs + lcol * 132 + mt * 16 + quad * 4) = p;
      }
#pragma unroll
      for (int ks = 0; ks < 4; ++ks) {
        const unsigned short* hp = hs + lcol * 132 + ks * 32 + quad * 8;
        bh[nt][ks].u[0] = *(const uint2*)hp;
        bh[nt][ks].u[1] = *(const uint2*)(hp + 4);
      }
    }

    // ---- uniform run loop over segments within the 64 nodes ----
    int p = 0;
    while (p < 64) {
      int pn = p >> 4, pl = p & 15;
      int sel = (pn == 0) ? sv[0] : (pn == 1) ? sv[1] : (pn == 2) ? sv[2] : sv[3];
      int s = __shfl(sel, pl);           // seg of first unprocessed node (uniform)
      if (s != cur_seg) { FLUSH(); cur_seg = s; }
      int cnt = 0;
      float em[4][4];
#pragma unroll
      for (int nt = 0; nt < 4; ++nt) {
        bool mm = (sv[nt] == s);
        cnt += (int)__popcll(__ballot(mm));
        float m = mm ? 1.f : 0.f;
#pragma unroll
        for (int h = 0; h < 4; ++h) em[nt][h] = e16[nt][h] * m;
      }
#pragma unroll
      for (int h = 0; h < 4; ++h)
        e_sum[h] += em[0][h] + em[1][h] + em[2][h] + em[3][h];
#pragma unroll
      for (int mt = 0; mt < 8; ++mt) {
        short8 a20 = *(const short8*)(mw2s + ((size_t)(mt * 4 + 0) * 64 + lane) * 8);
        short8 a21 = *(const short8*)(mw2s + ((size_t)(mt * 4 + 1) * 64 + lane) * 8);
        short8 a22 = *(const short8*)(mw2s + ((size_t)(mt * 4 + 2) * 64 + lane) * 8);
        short8 a23 = *(const short8*)(mw2s + ((size_t)(mt * 4 + 3) * 64 + lane) * 8);
        const int hh = mt >> 1;          // head of fcols [mt*16, mt*16+16)
#pragma unroll
        for (int nt = 0; nt < 4; ++nt) {
          floatx4 cc = {0.f, 0.f, 0.f, 0.f};
          cc = MFMA16(a20, bh[nt][0].s, cc);
          cc = MFMA16(a21, bh[nt][1].s, cc);
          cc = MFMA16(a22, bh[nt][2].s, cc);
          cc = MFMA16(a23, bh[nt][3].s, cc);
          float e = em[nt][hh];
          acc[mt][0] = fmaf(e, cc[0], acc[mt][0]);
          acc[mt][1] = fmaf(e, cc[1], acc[mt][1]);
          acc[mt][2] = fmaf(e, cc[2], acc[mt][2]);
          acc[mt][3] = fmaf(e, cc[3], acc[mt][3]);
        }
      }
      p += (cnt >> 2);                   // 4 quads replicate each node
    }
  }
  FLUSH();
}

// ---------------------------------------------------------------------------
// Finalize: out = numer/denom + b2 (b2 separable; scores sum to 1 per seg-head)
// ---------------------------------------------------------------------------
__global__ void finalize_kernel(float* __restrict__ out, const float* __restrict__ denom,
                                const float* __restrict__ b2) {
  int i = blockIdx.x * 256 + threadIdx.x;   // 131072 = 1024 segs * 128 fcols
  int seg = i >> 7, head = (i >> 5) & 3;
  float d = denom[seg * 4 + head];
  out[i] = (d > 0.f) ? (out[i] / d + b2[i & 127]) : 0.f;
}

// ---------------------------------------------------------------------------
extern "C" void kernel_launch(void* const* d_in, const int* in_sizes, int n_in,
                              void* d_out, int out_size, void* d_ws, size_t ws_size,
                              hipStream_t stream) {
  const float* x     = (const float*)d_in[0];
  const int*   batch = (const int*)d_in[1];
  // d_in[2] = num_segments (constant 1024, unused)
  const float* gw1 = (const float*)d_in[3];
  const float* pa  = (const float*)d_in[4];
  const float* gw2 = (const float*)d_in[5];
  const float* mw1 = (const float*)d_in[6];
  const float* mb1 = (const float*)d_in[7];
  const float* mw2 = (const float*)d_in[8];
  const float* mb2 = (const float*)d_in[9];
  float* out = (float*)d_out;

  char* ws = (char*)d_ws;
  float* denom = (float*)ws;                              // 4096 fp32 = 16,384 B
  unsigned short* gw1s = (unsigned short*)(ws + 16384);   // 32,768 B
  unsigned short* mw1s = (unsigned short*)(ws + 49152);   // 16,384 B
  unsigned short* mw2s = (unsigned short*)(ws + 65536);   // 32,768 B

  swizzle_weights<<<160, 256, 0, stream>>>(gw1, mw1, mw2, gw1s, mw1s, mw2s,
                                           denom, out);

  fused_kernel<<<NBLK, 128, 0, stream>>>(x, batch, gw1s, mw1s, mw2s, gw2,
                                         pa, mb1, denom, out);

  finalize_kernel<<<512, 256, 0, stream>>>(out, denom, mb2);
}

// Round 2
// 352.635 us; speedup vs baseline: 1.3013x; 1.3013x over previous
//
#include <hip/hip_runtime.h>
#include <cstdint>
#include <cstddef>

#define NN 500000            // nodes = 16 * 31250 exactly
#define NTILES 31250         // 16-node tiles
#define NG 15625             // 32-node granules (2 tiles each; NN%32==0, no tail)
#define NBLK 2048            // 128-thread blocks; 8/CU resident -> 16 waves/CU
#define NWAVES (NBLK * 2)
// IN_CH=64, HEADS=4, OUT_CH=32, F=128 out feats, GH=256 gate hidden, SEGS=1024

typedef __attribute__((ext_vector_type(8))) short short8;   // 8 bf16 MFMA frag
typedef __attribute__((ext_vector_type(4))) float floatx4;  // MFMA accumulator
typedef __attribute__((ext_vector_type(4))) float fv4;

__device__ __forceinline__ unsigned short f2bf(float f) {
  union { float f; unsigned u; } v; v.f = f;
  unsigned r = v.u + 0x7FFFu + ((v.u >> 16) & 1u);  // RNE
  return (unsigned short)(r >> 16);
}
__device__ __forceinline__ unsigned pack2bf(float a, float b) {
  return (unsigned)f2bf(a) | ((unsigned)f2bf(b) << 16);
}
__device__ __forceinline__ fv4 ntload4(const float* p) {
  return __builtin_nontemporal_load((const fv4*)p);
}

#define MFMA16(a, b, c) __builtin_amdgcn_mfma_f32_16x16x32_bf16((a), (b), (c), 0, 0, 0)

// ---------------------------------------------------------------------------
// Kernel W: fp32 weights -> bf16 MFMA A-fragment order (gw1 / mw1 / mw2 only;
// gw2 is consumed as fp32 via LDS in the fused kernel). Also zeroes the
// denom/out accumulators (folds the two hipMemsetAsync launches).
// dst[((mtile*ksteps+ks)*64+lane)*8+j] = W[mtile*16+(lane&15)][ks*32+(lane>>4)*8+j]
// ---------------------------------------------------------------------------
__global__ void swizzle_weights(const float* __restrict__ gw1, const float* __restrict__ mw1,
                                const float* __restrict__ mw2,
                                unsigned short* __restrict__ gw1s,
                                unsigned short* __restrict__ mw1s,
                                unsigned short* __restrict__ mw2s,
                                float* __restrict__ denom, float* __restrict__ out) {
  int e = blockIdx.x * 256 + threadIdx.x;   // 40960 total
  if (e < 4096) denom[e] = 0.f;
#pragma unroll
  for (int i = 0; i < 4; ++i) {             // 131072 = 1024 segs * 128 fcols
    int o = e + i * 40960;
    if (o < 131072) out[o] = 0.f;
  }
  const float* src; unsigned short* dst; int ksteps, K, local;
  if (e < 16384)      { src = gw1; dst = gw1s; ksteps = 2; K = 64;  local = e; }
  else if (e < 24576) { src = mw1; dst = mw1s; ksteps = 2; K = 64;  local = e - 16384; }
  else                { src = mw2; dst = mw2s; ksteps = 4; K = 128; local = e - 24576; }
  int j = local & 7, lane = (local >> 3) & 63, tile = local >> 9;
  int ks = tile % ksteps, mtile = tile / ksteps;
  int row = mtile * 16 + (lane & 15);
  int k   = ks * 32 + ((lane >> 4) & 3) * 8 + j;
  dst[local] = f2bf(src[row * K + k]);
}

#define FLUSH() do {                                                          \
  _Pragma("unroll") for (int mt_ = 0; mt_ < 8; ++mt_) {                       \
    _Pragma("unroll") for (int r_ = 0; r_ < 4; ++r_) {                        \
      float v_ = acc[mt_][r_];                                                \
      v_ += __shfl_xor(v_, 1); v_ += __shfl_xor(v_, 2);                       \
      v_ += __shfl_xor(v_, 4); v_ += __shfl_xor(v_, 8);                       \
      if (lcol == 0)                                                          \
        atomicAdd(&out[cur_seg * 128 + mt_ * 16 + quad * 4 + r_], v_);        \
      acc[mt_][r_] = 0.f; } }                                                 \
  _Pragma("unroll") for (int h_ = 0; h_ < 4; ++h_) {                          \
    float v_ = e_sum[h_];                                                     \
    v_ += __shfl_xor(v_, 1); v_ += __shfl_xor(v_, 2);                         \
    v_ += __shfl_xor(v_, 4); v_ += __shfl_xor(v_, 8);                         \
    if (lane == 0) atomicAdd(&denom[cur_seg * 4 + h_], v_);                   \
    e_sum[h_] = 0.f; }                                                        \
} while (0)

// ---------------------------------------------------------------------------
// Fused kernel, barrier-free after prologue: each WAVE owns contiguous 32-node
// granules (2 tiles). Weights streamed from global (L2-resident; x is
// nontemporal so it can't evict them). Gate L2 fused into gate L1 epilogue in
// VALU via gw2^T in LDS. MLP-L1 staging is per-16-node-tile (4.2 KB/wave).
// 32-node granule keeps the live register set (~110) under 128 so 4 waves/SIMD
// is reachable WITHOUT spilling (round-1 lesson: forcing 4 w/EU at ~156 live
// regs spilled 700 MB of scratch to HBM).
// Segment accumulation in registers, uniform run-loop, flush on seg change.
// ---------------------------------------------------------------------------
__global__ __launch_bounds__(128, 4) void fused_kernel(
    const float* __restrict__ x, const int* __restrict__ batch,
    const unsigned short* __restrict__ gw1s, const unsigned short* __restrict__ mw1s,
    const unsigned short* __restrict__ mw2s, const float* __restrict__ gw2,
    const float* __restrict__ prelu_a, const float* __restrict__ b1,
    float* __restrict__ denom, float* __restrict__ out) {
  __shared__ float gw2L[1024];                   // gw2^T [wcol][head], 4 KB
  __shared__ unsigned short hs_all[2][16 * 132]; // per-wave h1 staging, 2x4.2 KB
  const int t = threadIdx.x;
  const int wave = t >> 6, lane = t & 63;
  const int quad = lane >> 4, lcol = lane & 15;
  unsigned short* hs = hs_all[wave];

  for (int i = t; i < 1024; i += 128) gw2L[i] = gw2[(i & 3) * 256 + (i >> 2)];
  __syncthreads();   // only barrier in the kernel

  const float slope = prelu_a[0];
  const int W = blockIdx.x * 2 + wave;
  const int g0 = (int)(((long long)W * NG) / NWAVES);
  const int g1 = (int)(((long long)(W + 1) * NG) / NWAVES);

  float acc[8][4];
  float e_sum[4] = {0.f, 0.f, 0.f, 0.f};
#pragma unroll
  for (int mt = 0; mt < 8; ++mt)
#pragma unroll
    for (int r = 0; r < 4; ++r) acc[mt][r] = 0.f;
  int fs = g0 * 32; if (fs > NN - 1) fs = NN - 1;
  int cur_seg = batch[fs];

  for (int g = g0; g < g1; ++g) {
    const int base = g * 32;
    int sv[2];
    short8 bx[2][2];
#pragma unroll
    for (int nt = 0; nt < 2; ++nt) {
      int node = base + nt * 16 + lcol;    // NN%32==0 -> always valid
      sv[nt] = batch[node];
      const float* xp = x + (size_t)node * 64 + quad * 8;
      fv4 v0 = ntload4(xp), v1 = ntload4(xp + 4);
      fv4 v2 = ntload4(xp + 32), v3 = ntload4(xp + 36);
      union { short8 s; unsigned u[4]; } u0, u1;
      u0.u[0] = pack2bf(v0[0], v0[1]); u0.u[1] = pack2bf(v0[2], v0[3]);
      u0.u[2] = pack2bf(v1[0], v1[1]); u0.u[3] = pack2bf(v1[2], v1[3]);
      u1.u[0] = pack2bf(v2[0], v2[1]); u1.u[1] = pack2bf(v2[2], v2[3]);
      u1.u[2] = pack2bf(v3[0], v3[1]); u1.u[3] = pack2bf(v3[2], v3[3]);
      bx[nt][0] = u0.s; bx[nt][1] = u1.s;
    }

    // ---- gate L1 (MFMA) with fused L2 partials (VALU, gw2L broadcast) ----
    float gp[2][4];
#pragma unroll
    for (int nt = 0; nt < 2; ++nt)
#pragma unroll
      for (int h = 0; h < 4; ++h) gp[nt][h] = 0.f;
#pragma unroll 2
    for (int mt = 0; mt < 16; ++mt) {
      short8 a0 = *(const short8*)(gw1s + ((size_t)(mt * 2 + 0) * 64 + lane) * 8);
      short8 a1 = *(const short8*)(gw1s + ((size_t)(mt * 2 + 1) * 64 + lane) * 8);
      fv4 g2r0 = *(const fv4*)&gw2L[(mt * 16 + quad * 4 + 0) * 4];
      fv4 g2r1 = *(const fv4*)&gw2L[(mt * 16 + quad * 4 + 1) * 4];
      fv4 g2r2 = *(const fv4*)&gw2L[(mt * 16 + quad * 4 + 2) * 4];
      fv4 g2r3 = *(const fv4*)&gw2L[(mt * 16 + quad * 4 + 3) * 4];
#pragma unroll
      for (int nt = 0; nt < 2; ++nt) {
        floatx4 cc = {0.f, 0.f, 0.f, 0.f};
        cc = MFMA16(a0, bx[nt][0], cc);
        cc = MFMA16(a1, bx[nt][1], cc);
        float h0 = cc[0] >= 0.f ? cc[0] : slope * cc[0];
        float h1v = cc[1] >= 0.f ? cc[1] : slope * cc[1];
        float h2 = cc[2] >= 0.f ? cc[2] : slope * cc[2];
        float h3 = cc[3] >= 0.f ? cc[3] : slope * cc[3];
        gp[nt][0] += g2r0[0]*h0 + g2r1[0]*h1v + g2r2[0]*h2 + g2r3[0]*h3;
        gp[nt][1] += g2r0[1]*h0 + g2r1[1]*h1v + g2r2[1]*h2 + g2r3[1]*h3;
        gp[nt][2] += g2r0[2]*h0 + g2r1[2]*h1v + g2r2[2]*h2 + g2r3[2]*h3;
        gp[nt][3] += g2r0[3]*h0 + g2r1[3]*h1v + g2r2[3]*h2 + g2r3[3]*h3;
      }
    }
    float e16[2][4];
#pragma unroll
    for (int nt = 0; nt < 2; ++nt)
#pragma unroll
      for (int h = 0; h < 4; ++h) {
        float v = gp[nt][h];
        v += __shfl_xor(v, 16);      // sum partials across quads
        v += __shfl_xor(v, 32);
        e16[nt][h] = __expf(v);      // |gate| small -> no max needed
      }

    // ---- MLP L1 (MFMA) -> per-tile bf16 staging -> B-fragments for L2 ----
    // nt-outer so the staging buffer covers only 16 nodes (LDS 4.2 KB/wave);
    // wave-internal LDS ordering handles the write->read->overwrite chain.
    union BH { short8 s; uint2 u[2]; } bh[2][4];
#pragma unroll
    for (int nt = 0; nt < 2; ++nt) {
#pragma unroll 2
      for (int mt = 0; mt < 8; ++mt) {
        short8 a0 = *(const short8*)(mw1s + ((size_t)(mt * 2 + 0) * 64 + lane) * 8);
        short8 a1 = *(const short8*)(mw1s + ((size_t)(mt * 2 + 1) * 64 + lane) * 8);
        fv4 bias = *(const fv4*)(b1 + mt * 16 + quad * 4);
        floatx4 cc = {0.f, 0.f, 0.f, 0.f};
        cc = MFMA16(a0, bx[nt][0], cc);
        cc = MFMA16(a1, bx[nt][1], cc);
        uint2 p;
        p.x = pack2bf(fmaxf(cc[0] + bias[0], 0.f), fmaxf(cc[1] + bias[1], 0.f));
        p.y = pack2bf(fmaxf(cc[2] + bias[2], 0.f), fmaxf(cc[3] + bias[3], 0.f));
        *(uint2*)(hs + lcol * 132 + mt * 16 + quad * 4) = p;
      }
#pragma unroll
      for (int ks = 0; ks < 4; ++ks) {
        const unsigned short* hp = hs + lcol * 132 + ks * 32 + quad * 8;
        bh[nt][ks].u[0] = *(const uint2*)hp;
        bh[nt][ks].u[1] = *(const uint2*)(hp + 4);
      }
    }

    // ---- uniform run loop over segments within the 32 nodes ----
    int p = 0;
    while (p < 32) {
      int sel = (p >> 4) ? sv[1] : sv[0];
      int s = __shfl(sel, p & 15);       // seg of first unprocessed node (uniform)
      if (s != cur_seg) { FLUSH(); cur_seg = s; }
      int cnt = 0;
      float em[2][4];
#pragma unroll
      for (int nt = 0; nt < 2; ++nt) {
        bool mm = (sv[nt] == s);
        cnt += (int)__popcll(__ballot(mm));
        float m = mm ? 1.f : 0.f;
#pragma unroll
        for (int h = 0; h < 4; ++h) em[nt][h] = e16[nt][h] * m;
      }
#pragma unroll
      for (int h = 0; h < 4; ++h)
        e_sum[h] += em[0][h] + em[1][h];
#pragma unroll
      for (int mt = 0; mt < 8; ++mt) {
        short8 a20 = *(const short8*)(mw2s + ((size_t)(mt * 4 + 0) * 64 + lane) * 8);
        short8 a21 = *(const short8*)(mw2s + ((size_t)(mt * 4 + 1) * 64 + lane) * 8);
        short8 a22 = *(const short8*)(mw2s + ((size_t)(mt * 4 + 2) * 64 + lane) * 8);
        short8 a23 = *(const short8*)(mw2s + ((size_t)(mt * 4 + 3) * 64 + lane) * 8);
        const int hh = mt >> 1;          // head of fcols [mt*16, mt*16+16)
#pragma unroll
        for (int nt = 0; nt < 2; ++nt) {
          floatx4 cc = {0.f, 0.f, 0.f, 0.f};
          cc = MFMA16(a20, bh[nt][0].s, cc);
          cc = MFMA16(a21, bh[nt][1].s, cc);
          cc = MFMA16(a22, bh[nt][2].s, cc);
          cc = MFMA16(a23, bh[nt][3].s, cc);
          float e = em[nt][hh];
          acc[mt][0] = fmaf(e, cc[0], acc[mt][0]);
          acc[mt][1] = fmaf(e, cc[1], acc[mt][1]);
          acc[mt][2] = fmaf(e, cc[2], acc[mt][2]);
          acc[mt][3] = fmaf(e, cc[3], acc[mt][3]);
        }
      }
      p += (cnt >> 2);                   // 4 quads replicate each node
    }
  }
  FLUSH();
}

// ---------------------------------------------------------------------------
// Finalize: out = numer/denom + b2 (b2 separable; scores sum to 1 per seg-head)
// ---------------------------------------------------------------------------
__global__ void finalize_kernel(float* __restrict__ out, const float* __restrict__ denom,
                                const float* __restrict__ b2) {
  int i = blockIdx.x * 256 + threadIdx.x;   // 131072 = 1024 segs * 128 fcols
  int seg = i >> 7, head = (i >> 5) & 3;
  float d = denom[seg * 4 + head];
  out[i] = (d > 0.f) ? (out[i] / d + b2[i & 127]) : 0.f;
}

// ---------------------------------------------------------------------------
extern "C" void kernel_launch(void* const* d_in, const int* in_sizes, int n_in,
                              void* d_out, int out_size, void* d_ws, size_t ws_size,
                              hipStream_t stream) {
  const float* x     = (const float*)d_in[0];
  const int*   batch = (const int*)d_in[1];
  // d_in[2] = num_segments (constant 1024, unused)
  const float* gw1 = (const float*)d_in[3];
  const float* pa  = (const float*)d_in[4];
  const float* gw2 = (const float*)d_in[5];
  const float* mw1 = (const float*)d_in[6];
  const float* mb1 = (const float*)d_in[7];
  const float* mw2 = (const float*)d_in[8];
  const float* mb2 = (const float*)d_in[9];
  float* out = (float*)d_out;

  char* ws = (char*)d_ws;
  float* denom = (float*)ws;                              // 4096 fp32 = 16,384 B
  unsigned short* gw1s = (unsigned short*)(ws + 16384);   // 32,768 B
  unsigned short* mw1s = (unsigned short*)(ws + 49152);   // 16,384 B
  unsigned short* mw2s = (unsigned short*)(ws + 65536);   // 32,768 B

  swizzle_weights<<<160, 256, 0, stream>>>(gw1, mw1, mw2, gw1s, mw1s, mw2s,
                                           denom, out);

  fused_kernel<<<NBLK, 128, 0, stream>>>(x, batch, gw1s, mw1s, mw2s, gw2,
                                         pa, mb1, denom, out);

  finalize_kernel<<<512, 256, 0, stream>>>(out, denom, mb2);
}

// Round 3
// 344.757 us; speedup vs baseline: 1.3311x; 1.0229x over previous
//
#include <hip/hip_runtime.h>
#include <cstdint>
#include <cstddef>

#define NN 500000            // nodes = 16 * 31250 exactly
#define NTILES 31250         // 16-node tiles
#define NG 15625             // 32-node granules (2 tiles each; NN%32==0, no tail)
#define NBLK 1536            // 128-thread blocks; 6/CU resident -> 12 waves/CU
#define NWAVES (NBLK * 2)
// IN_CH=64, HEADS=4, OUT_CH=32, F=128 out feats, GH=256 gate hidden, SEGS=1024

typedef __attribute__((ext_vector_type(8))) short short8;   // 8 bf16 MFMA frag
typedef __attribute__((ext_vector_type(4))) float floatx4;  // MFMA accumulator
typedef __attribute__((ext_vector_type(4))) float fv4;

__device__ __forceinline__ unsigned short f2bf(float f) {
  union { float f; unsigned u; } v; v.f = f;
  unsigned r = v.u + 0x7FFFu + ((v.u >> 16) & 1u);  // RNE
  return (unsigned short)(r >> 16);
}
__device__ __forceinline__ unsigned pack2bf(float a, float b) {
  return (unsigned)f2bf(a) | ((unsigned)f2bf(b) << 16);
}
__device__ __forceinline__ fv4 ntload4(const float* p) {
  return __builtin_nontemporal_load((const fv4*)p);
}

#define MFMA16(a, b, c) __builtin_amdgcn_mfma_f32_16x16x32_bf16((a), (b), (c), 0, 0, 0)

// ---------------------------------------------------------------------------
// Kernel W: fp32 weights -> bf16 MFMA A-fragment order (gw1 / mw1 / mw2 only;
// gw2 is consumed as fp32 via LDS in the fused kernel). Also zeroes the
// denom/out accumulators (folds the two hipMemsetAsync launches).
// dst[((mtile*ksteps+ks)*64+lane)*8+j] = W[mtile*16+(lane&15)][ks*32+(lane>>4)*8+j]
// ---------------------------------------------------------------------------
__global__ void swizzle_weights(const float* __restrict__ gw1, const float* __restrict__ mw1,
                                const float* __restrict__ mw2,
                                unsigned short* __restrict__ gw1s,
                                unsigned short* __restrict__ mw1s,
                                unsigned short* __restrict__ mw2s,
                                float* __restrict__ denom, float* __restrict__ out) {
  int e = blockIdx.x * 256 + threadIdx.x;   // 40960 total
  if (e < 4096) denom[e] = 0.f;
#pragma unroll
  for (int i = 0; i < 4; ++i) {             // 131072 = 1024 segs * 128 fcols
    int o = e + i * 40960;
    if (o < 131072) out[o] = 0.f;
  }
  const float* src; unsigned short* dst; int ksteps, K, local;
  if (e < 16384)      { src = gw1; dst = gw1s; ksteps = 2; K = 64;  local = e; }
  else if (e < 24576) { src = mw1; dst = mw1s; ksteps = 2; K = 64;  local = e - 16384; }
  else                { src = mw2; dst = mw2s; ksteps = 4; K = 128; local = e - 24576; }
  int j = local & 7, lane = (local >> 3) & 63, tile = local >> 9;
  int ks = tile % ksteps, mtile = tile / ksteps;
  int row = mtile * 16 + (lane & 15);
  int k   = ks * 32 + ((lane >> 4) & 3) * 8 + j;
  dst[local] = f2bf(src[row * K + k]);
}

#define FLUSH() do {                                                          \
  _Pragma("unroll") for (int mt_ = 0; mt_ < 8; ++mt_) {                       \
    _Pragma("unroll") for (int r_ = 0; r_ < 4; ++r_) {                        \
      float v_ = acc[mt_][r_];                                                \
      v_ += __shfl_xor(v_, 1); v_ += __shfl_xor(v_, 2);                       \
      v_ += __shfl_xor(v_, 4); v_ += __shfl_xor(v_, 8);                       \
      if (lcol == 0)                                                          \
        atomicAdd(&out[cur_seg * 128 + mt_ * 16 + quad * 4 + r_], v_);        \
      acc[mt_][r_] = 0.f; } }                                                 \
  _Pragma("unroll") for (int h_ = 0; h_ < 4; ++h_) {                          \
    float v_ = e_sum[h_];                                                     \
    v_ += __shfl_xor(v_, 1); v_ += __shfl_xor(v_, 2);                         \
    v_ += __shfl_xor(v_, 4); v_ += __shfl_xor(v_, 8);                         \
    if (lane == 0) atomicAdd(&denom[cur_seg * 4 + h_], v_);                   \
    e_sum[h_] = 0.f; }                                                        \
} while (0)

// ---------------------------------------------------------------------------
// Fused kernel, barrier-free after prologue: each WAVE owns contiguous 32-node
// granules (2 tiles). Weights streamed from global (L2-resident; x is
// nontemporal so it can't evict them). Gate L2 fused into gate L1 epilogue in
// VALU via gw2^T in LDS. MLP-L1 staging is per-16-node-tile (4.2 KB/wave).
// __launch_bounds__(128,3): budget 512/3=168 regs/wave. Round-1/2 lesson:
// (128,4) = 128-reg budget minus the MFMA AGPR carve-out left only 64 arch
// VGPRs (rocprof VGPR_Count=64) -> deterministic ~40-reg spill per granule
// (FETCH 364 MB / WRITE 167 MB vs ~130/2 ideal). 3 waves/SIMD = 12 waves/CU
// is still 1.5x the original 8, now spill-free.
// Segment accumulation in registers, uniform run-loop, flush on seg change.
// ---------------------------------------------------------------------------
__global__ __launch_bounds__(128, 3) void fused_kernel(
    const float* __restrict__ x, const int* __restrict__ batch,
    const unsigned short* __restrict__ gw1s, const unsigned short* __restrict__ mw1s,
    const unsigned short* __restrict__ mw2s, const float* __restrict__ gw2,
    const float* __restrict__ prelu_a, const float* __restrict__ b1,
    float* __restrict__ denom, float* __restrict__ out) {
  __shared__ float gw2L[1024];                   // gw2^T [wcol][head], 4 KB
  __shared__ unsigned short hs_all[2][16 * 132]; // per-wave h1 staging, 2x4.2 KB
  const int t = threadIdx.x;
  const int wave = t >> 6, lane = t & 63;
  const int quad = lane >> 4, lcol = lane & 15;
  unsigned short* hs = hs_all[wave];

  for (int i = t; i < 1024; i += 128) gw2L[i] = gw2[(i & 3) * 256 + (i >> 2)];
  __syncthreads();   // only barrier in the kernel

  const float slope = prelu_a[0];
  const int W = blockIdx.x * 2 + wave;
  const int g0 = (int)(((long long)W * NG) / NWAVES);
  const int g1 = (int)(((long long)(W + 1) * NG) / NWAVES);

  float acc[8][4];
  float e_sum[4] = {0.f, 0.f, 0.f, 0.f};
#pragma unroll
  for (int mt = 0; mt < 8; ++mt)
#pragma unroll
    for (int r = 0; r < 4; ++r) acc[mt][r] = 0.f;
  int fs = g0 * 32; if (fs > NN - 1) fs = NN - 1;
  int cur_seg = batch[fs];

  for (int g = g0; g < g1; ++g) {
    const int base = g * 32;
    int sv[2];
    short8 bx[2][2];
#pragma unroll
    for (int nt = 0; nt < 2; ++nt) {
      int node = base + nt * 16 + lcol;    // NN%32==0 -> always valid
      sv[nt] = batch[node];
      const float* xp = x + (size_t)node * 64 + quad * 8;
      fv4 v0 = ntload4(xp), v1 = ntload4(xp + 4);
      fv4 v2 = ntload4(xp + 32), v3 = ntload4(xp + 36);
      union { short8 s; unsigned u[4]; } u0, u1;
      u0.u[0] = pack2bf(v0[0], v0[1]); u0.u[1] = pack2bf(v0[2], v0[3]);
      u0.u[2] = pack2bf(v1[0], v1[1]); u0.u[3] = pack2bf(v1[2], v1[3]);
      u1.u[0] = pack2bf(v2[0], v2[1]); u1.u[1] = pack2bf(v2[2], v2[3]);
      u1.u[2] = pack2bf(v3[0], v3[1]); u1.u[3] = pack2bf(v3[2], v3[3]);
      bx[nt][0] = u0.s; bx[nt][1] = u1.s;
    }

    // ---- gate L1 (MFMA) with fused L2 partials (VALU, gw2L broadcast) ----
    float gp[2][4];
#pragma unroll
    for (int nt = 0; nt < 2; ++nt)
#pragma unroll
      for (int h = 0; h < 4; ++h) gp[nt][h] = 0.f;
#pragma unroll 2
    for (int mt = 0; mt < 16; ++mt) {
      short8 a0 = *(const short8*)(gw1s + ((size_t)(mt * 2 + 0) * 64 + lane) * 8);
      short8 a1 = *(const short8*)(gw1s + ((size_t)(mt * 2 + 1) * 64 + lane) * 8);
      fv4 g2r0 = *(const fv4*)&gw2L[(mt * 16 + quad * 4 + 0) * 4];
      fv4 g2r1 = *(const fv4*)&gw2L[(mt * 16 + quad * 4 + 1) * 4];
      fv4 g2r2 = *(const fv4*)&gw2L[(mt * 16 + quad * 4 + 2) * 4];
      fv4 g2r3 = *(const fv4*)&gw2L[(mt * 16 + quad * 4 + 3) * 4];
#pragma unroll
      for (int nt = 0; nt < 2; ++nt) {
        floatx4 cc = {0.f, 0.f, 0.f, 0.f};
        cc = MFMA16(a0, bx[nt][0], cc);
        cc = MFMA16(a1, bx[nt][1], cc);
        float h0 = cc[0] >= 0.f ? cc[0] : slope * cc[0];
        float h1v = cc[1] >= 0.f ? cc[1] : slope * cc[1];
        float h2 = cc[2] >= 0.f ? cc[2] : slope * cc[2];
        float h3 = cc[3] >= 0.f ? cc[3] : slope * cc[3];
        gp[nt][0] += g2r0[0]*h0 + g2r1[0]*h1v + g2r2[0]*h2 + g2r3[0]*h3;
        gp[nt][1] += g2r0[1]*h0 + g2r1[1]*h1v + g2r2[1]*h2 + g2r3[1]*h3;
        gp[nt][2] += g2r0[2]*h0 + g2r1[2]*h1v + g2r2[2]*h2 + g2r3[2]*h3;
        gp[nt][3] += g2r0[3]*h0 + g2r1[3]*h1v + g2r2[3]*h2 + g2r3[3]*h3;
      }
    }
    float e16[2][4];
#pragma unroll
    for (int nt = 0; nt < 2; ++nt)
#pragma unroll
      for (int h = 0; h < 4; ++h) {
        float v = gp[nt][h];
        v += __shfl_xor(v, 16);      // sum partials across quads
        v += __shfl_xor(v, 32);
        e16[nt][h] = __expf(v);      // |gate| small -> no max needed
      }

    // ---- MLP L1 (MFMA) -> per-tile bf16 staging -> B-fragments for L2 ----
    // nt-outer so the staging buffer covers only 16 nodes (LDS 4.2 KB/wave);
    // wave-internal LDS ordering handles the write->read->overwrite chain.
    union BH { short8 s; uint2 u[2]; } bh[2][4];
#pragma unroll
    for (int nt = 0; nt < 2; ++nt) {
#pragma unroll 2
      for (int mt = 0; mt < 8; ++mt) {
        short8 a0 = *(const short8*)(mw1s + ((size_t)(mt * 2 + 0) * 64 + lane) * 8);
        short8 a1 = *(const short8*)(mw1s + ((size_t)(mt * 2 + 1) * 64 + lane) * 8);
        fv4 bias = *(const fv4*)(b1 + mt * 16 + quad * 4);
        floatx4 cc = {0.f, 0.f, 0.f, 0.f};
        cc = MFMA16(a0, bx[nt][0], cc);
        cc = MFMA16(a1, bx[nt][1], cc);
        uint2 p;
        p.x = pack2bf(fmaxf(cc[0] + bias[0], 0.f), fmaxf(cc[1] + bias[1], 0.f));
        p.y = pack2bf(fmaxf(cc[2] + bias[2], 0.f), fmaxf(cc[3] + bias[3], 0.f));
        *(uint2*)(hs + lcol * 132 + mt * 16 + quad * 4) = p;
      }
#pragma unroll
      for (int ks = 0; ks < 4; ++ks) {
        const unsigned short* hp = hs + lcol * 132 + ks * 32 + quad * 8;
        bh[nt][ks].u[0] = *(const uint2*)hp;
        bh[nt][ks].u[1] = *(const uint2*)(hp + 4);
      }
    }

    // ---- uniform run loop over segments within the 32 nodes ----
    int p = 0;
    while (p < 32) {
      int sel = (p >> 4) ? sv[1] : sv[0];
      int s = __shfl(sel, p & 15);       // seg of first unprocessed node (uniform)
      if (s != cur_seg) { FLUSH(); cur_seg = s; }
      int cnt = 0;
      float em[2][4];
#pragma unroll
      for (int nt = 0; nt < 2; ++nt) {
        bool mm = (sv[nt] == s);
        cnt += (int)__popcll(__ballot(mm));
        float m = mm ? 1.f : 0.f;
#pragma unroll
        for (int h = 0; h < 4; ++h) em[nt][h] = e16[nt][h] * m;
      }
#pragma unroll
      for (int h = 0; h < 4; ++h)
        e_sum[h] += em[0][h] + em[1][h];
#pragma unroll
      for (int mt = 0; mt < 8; ++mt) {
        short8 a20 = *(const short8*)(mw2s + ((size_t)(mt * 4 + 0) * 64 + lane) * 8);
        short8 a21 = *(const short8*)(mw2s + ((size_t)(mt * 4 + 1) * 64 + lane) * 8);
        short8 a22 = *(const short8*)(mw2s + ((size_t)(mt * 4 + 2) * 64 + lane) * 8);
        short8 a23 = *(const short8*)(mw2s + ((size_t)(mt * 4 + 3) * 64 + lane) * 8);
        const int hh = mt >> 1;          // head of fcols [mt*16, mt*16+16)
#pragma unroll
        for (int nt = 0; nt < 2; ++nt) {
          floatx4 cc = {0.f, 0.f, 0.f, 0.f};
          cc = MFMA16(a20, bh[nt][0].s, cc);
          cc = MFMA16(a21, bh[nt][1].s, cc);
          cc = MFMA16(a22, bh[nt][2].s, cc);
          cc = MFMA16(a23, bh[nt][3].s, cc);
          float e = em[nt][hh];
          acc[mt][0] = fmaf(e, cc[0], acc[mt][0]);
          acc[mt][1] = fmaf(e, cc[1], acc[mt][1]);
          acc[mt][2] = fmaf(e, cc[2], acc[mt][2]);
          acc[mt][3] = fmaf(e, cc[3], acc[mt][3]);
        }
      }
      p += (cnt >> 2);                   // 4 quads replicate each node
    }
  }
  FLUSH();
}

// ---------------------------------------------------------------------------
// Finalize: out = numer/denom + b2 (b2 separable; scores sum to 1 per seg-head)
// ---------------------------------------------------------------------------
__global__ void finalize_kernel(float* __restrict__ out, const float* __restrict__ denom,
                                const float* __restrict__ b2) {
  int i = blockIdx.x * 256 + threadIdx.x;   // 131072 = 1024 segs * 128 fcols
  int seg = i >> 7, head = (i >> 5) & 3;
  float d = denom[seg * 4 + head];
  out[i] = (d > 0.f) ? (out[i] / d + b2[i & 127]) : 0.f;
}

// ---------------------------------------------------------------------------
extern "C" void kernel_launch(void* const* d_in, const int* in_sizes, int n_in,
                              void* d_out, int out_size, void* d_ws, size_t ws_size,
                              hipStream_t stream) {
  const float* x     = (const float*)d_in[0];
  const int*   batch = (const int*)d_in[1];
  // d_in[2] = num_segments (constant 1024, unused)
  const float* gw1 = (const float*)d_in[3];
  const float* pa  = (const float*)d_in[4];
  const float* gw2 = (const float*)d_in[5];
  const float* mw1 = (const float*)d_in[6];
  const float* mb1 = (const float*)d_in[7];
  const float* mw2 = (const float*)d_in[8];
  const float* mb2 = (const float*)d_in[9];
  float* out = (float*)d_out;

  char* ws = (char*)d_ws;
  float* denom = (float*)ws;                              // 4096 fp32 = 16,384 B
  unsigned short* gw1s = (unsigned short*)(ws + 16384);   // 32,768 B
  unsigned short* mw1s = (unsigned short*)(ws + 49152);   // 16,384 B
  unsigned short* mw2s = (unsigned short*)(ws + 65536);   // 32,768 B

  swizzle_weights<<<160, 256, 0, stream>>>(gw1, mw1, mw2, gw1s, mw1s, mw2s,
                                           denom, out);

  fused_kernel<<<NBLK, 128, 0, stream>>>(x, batch, gw1s, mw1s, mw2s, gw2,
                                         pa, mb1, denom, out);

  finalize_kernel<<<512, 256, 0, stream>>>(out, denom, mb2);
}